// Round 1
// baseline (290.274 us; speedup 1.0000x reference)
//
#include <hip/hip_runtime.h>
#include <math.h>

// DecoderLayer: B=4,N=1,S=256,D=128,H=128,DFF=512, fp32 end-to-end.
// Algebraic simplifications used:
//  - self-attn: q=k=v=x  => sym term2[q,k] == term1[k,q] (transpose), computed once
//  - softmax is shift-invariant => b2 (scalar per row) dropped entirely
//  - b1 folded into the q-side MLP projection bias
//  - RES_RATIO=1.0 => residual is plain add

#define LN_EPS 1e-6f
#define NEGV  (-1e9f)

constexpr int B = 4, S = 256, D = 128, H = 128, DFF = 512;
constexpr int R = B * S; // 1024 rows total (N=1)

// ---------------- generic row-broadcast matmul: out[R,C] = A[R,K] @ W[K,C] + bias ----------------
template<int K, int C, bool RELU>
__global__ __launch_bounds__(256) void mm_kernel(
    const float* __restrict__ A, const float* __restrict__ W,
    const float* __restrict__ bias, float* __restrict__ out)
{
    constexpr int C4 = C / 4;        // float4 cols
    constexpr int ROWS = 256 / C4;   // rows per block
    __shared__ float Ash[ROWS * K];
    const int r0 = blockIdx.x * ROWS;

    const float4* Ag = (const float4*)(A + (size_t)r0 * K);
    float4* As4 = (float4*)Ash;
    for (int i = threadIdx.x; i < ROWS * K / 4; i += 256) As4[i] = Ag[i];
    __syncthreads();

    const int lr = threadIdx.x / C4;
    const int c4 = threadIdx.x % C4;
    const float4* W4 = (const float4*)W;
    float4 acc = make_float4(0.f, 0.f, 0.f, 0.f);
    #pragma unroll 8
    for (int k = 0; k < K; ++k) {
        const float a = Ash[lr * K + k];
        const float4 w = W4[k * C4 + c4];
        acc.x = fmaf(a, w.x, acc.x);
        acc.y = fmaf(a, w.y, acc.y);
        acc.z = fmaf(a, w.z, acc.z);
        acc.w = fmaf(a, w.w, acc.w);
    }
    if (bias) {
        const float4 bv = ((const float4*)bias)[c4];
        acc.x += bv.x; acc.y += bv.y; acc.z += bv.z; acc.w += bv.w;
    }
    if (RELU) {
        acc.x = fmaxf(acc.x, 0.f); acc.y = fmaxf(acc.y, 0.f);
        acc.z = fmaxf(acc.z, 0.f); acc.w = fmaxf(acc.w, 0.f);
    }
    ((float4*)out)[(size_t)(r0 + lr) * C4 + c4] = acc;
}

// ---------------- batched attn@v: out[b,q,d] = sum_k attn[b,q,k] * V[b,k,d] ----------------
__global__ __launch_bounds__(256) void bmm_av_kernel(
    const float* __restrict__ Attn,  // [B*S, S]
    const float* __restrict__ V,     // [B*S, D]
    float* __restrict__ out)         // [B*S, D]
{
    constexpr int C4 = D / 4;        // 32
    constexpr int ROWS = 256 / C4;   // 8
    __shared__ float Ash[ROWS * S];
    const int r0 = blockIdx.x * ROWS;
    const int b  = r0 / S;

    const float4* Ag = (const float4*)(Attn + (size_t)r0 * S);
    float4* As4 = (float4*)Ash;
    for (int i = threadIdx.x; i < ROWS * S / 4; i += 256) As4[i] = Ag[i];
    __syncthreads();

    const int lr = threadIdx.x / C4;
    const int c4 = threadIdx.x % C4;
    const float4* V4 = (const float4*)(V + (size_t)b * S * D);
    float4 acc = make_float4(0.f, 0.f, 0.f, 0.f);
    #pragma unroll 8
    for (int k = 0; k < S; ++k) {
        const float a = Ash[lr * S + k];
        const float4 v = V4[k * C4 + c4];
        acc.x = fmaf(a, v.x, acc.x);
        acc.y = fmaf(a, v.y, acc.y);
        acc.z = fmaf(a, v.z, acc.z);
        acc.w = fmaf(a, v.w, acc.w);
    }
    ((float4*)out)[(size_t)(r0 + lr) * C4 + c4] = acc;
}

// ---------------- pairwise score: S[b,q,k] (+)= sum_h relu(Aq[b,q,h] + Bk[b,k,h]) * W2[h] ----------------
// b1 must already be folded into Aq. 32x32 tile per block, 2x2 per thread.
__global__ __launch_bounds__(256) void pairwise_kernel(
    const float* __restrict__ Aq,   // [B*S, H] (bias folded)
    const float* __restrict__ Bk,   // [B*S, H]
    const float* __restrict__ W2,   // [H]
    float* __restrict__ Sout,       // [B, S, S]
    int accumulate)
{
    constexpr int TQ = 32, TK = 32;
    __shared__ float As[TQ][H + 1];
    __shared__ float Bs[TK][H + 1];
    __shared__ float W2s[H];

    const int b  = blockIdx.z;
    const int q0 = blockIdx.y * TQ;
    const int k0 = blockIdx.x * TK;
    const int tid = threadIdx.x;
    const int bS = b * S;

    for (int i = tid; i < TQ * H; i += 256) {
        const int r = i >> 7, c = i & (H - 1);
        As[r][c] = Aq[((size_t)(bS + q0 + r) << 7) + c];
    }
    for (int i = tid; i < TK * H; i += 256) {
        const int r = i >> 7, c = i & (H - 1);
        Bs[r][c] = Bk[((size_t)(bS + k0 + r) << 7) + c];
    }
    if (tid < H) W2s[tid] = W2[tid];
    __syncthreads();

    const int tx = tid & 15;   // k dir
    const int ty = tid >> 4;   // q dir
    float acc00 = 0.f, acc01 = 0.f, acc10 = 0.f, acc11 = 0.f;
    #pragma unroll 4
    for (int h = 0; h < H; ++h) {
        const float w  = W2s[h];
        const float a0 = As[2 * ty][h];
        const float a1 = As[2 * ty + 1][h];
        const float b0 = Bs[2 * tx][h];
        const float b1 = Bs[2 * tx + 1][h];
        acc00 = fmaf(fmaxf(a0 + b0, 0.f), w, acc00);
        acc01 = fmaf(fmaxf(a0 + b1, 0.f), w, acc01);
        acc10 = fmaf(fmaxf(a1 + b0, 0.f), w, acc10);
        acc11 = fmaf(fmaxf(a1 + b1, 0.f), w, acc11);
    }

    const size_t base = ((size_t)(bS + q0 + 2 * ty)) * S + (k0 + 2 * tx);
    if (accumulate) {
        Sout[base]         += acc00;
        Sout[base + 1]     += acc01;
        Sout[base + S]     += acc10;
        Sout[base + S + 1] += acc11;
    } else {
        Sout[base]         = acc00;
        Sout[base + 1]     = acc01;
        Sout[base + S]     = acc10;
        Sout[base + S + 1] = acc11;
    }
}

// ---------------- softmax over k (one block per (b,q) row); SYM adds transpose term ----------------
template<bool SYM>
__global__ __launch_bounds__(256) void softmax_kernel(
    const float* __restrict__ Sin,   // [B,S,S]
    const float* __restrict__ mask,  // [B,N,S,S]
    float* __restrict__ attn)        // [B,S,S]
{
    const int row = blockIdx.x;      // b*S + q
    const int b = row >> 8;
    const int q = row & (S - 1);
    const int k = threadIdx.x;

    float l = Sin[(size_t)row * S + k];
    if (SYM) l += Sin[((size_t)(b * S + k)) * S + q];
    l += mask[(size_t)row * S + k] * NEGV;

    __shared__ float red[256];
    red[k] = l;
    __syncthreads();
    for (int s = 128; s > 0; s >>= 1) {
        if (k < s) red[k] = fmaxf(red[k], red[k + s]);
        __syncthreads();
    }
    const float m = red[0];
    __syncthreads();
    const float e = __expf(l - m);
    red[k] = e;
    __syncthreads();
    for (int s = 128; s > 0; s >>= 1) {
        if (k < s) red[k] += red[k + s];
        __syncthreads();
    }
    attn[(size_t)row * S + k] = e * (1.f / red[0]);
}

// ---------------- fused residual-add + layernorm: out = LN(Aa + Bres) * g + beta ----------------
__global__ __launch_bounds__(64) void lnres_kernel(
    const float* __restrict__ Aa, const float* __restrict__ Bres,
    const float* __restrict__ g, const float* __restrict__ be,
    float* __restrict__ out)
{
    const int row = blockIdx.x;
    const int lane = threadIdx.x;   // 0..63, 2 elems each (D=128)
    const float2 a = ((const float2*)(Aa   + (size_t)row * D))[lane];
    const float2 b = ((const float2*)(Bres + (size_t)row * D))[lane];
    const float x0 = a.x + b.x, x1 = a.y + b.y;

    float s  = x0 + x1;
    float s2 = x0 * x0 + x1 * x1;
    for (int o = 32; o > 0; o >>= 1) {
        s  += __shfl_xor(s, o, 64);
        s2 += __shfl_xor(s2, o, 64);
    }
    const float m   = s * (1.f / D);
    const float var = s2 * (1.f / D) - m * m;
    const float rs  = rsqrtf(var + LN_EPS);

    const float2 gv = ((const float2*)g)[lane];
    const float2 bv = ((const float2*)be)[lane];
    float2 o2;
    o2.x = (x0 - m) * rs * gv.x + bv.x;
    o2.y = (x1 - m) * rs * gv.y + bv.y;
    ((float2*)(out + (size_t)row * D))[lane] = o2;
}

extern "C" void kernel_launch(void* const* d_in, const int* in_sizes, int n_in,
                              void* d_out, int out_size, void* d_ws, size_t ws_size,
                              hipStream_t stream) {
    (void)in_sizes; (void)n_in; (void)out_size; (void)ws_size;
    const float* x        = (const float*)d_in[0];
    const float* enc      = (const float*)d_in[1];
    const float* com_mask = (const float*)d_in[2];
    const float* dec_mask = (const float*)d_in[3];
    const float* W1q = (const float*)d_in[4];
    const float* W1k = (const float*)d_in[5];
    const float* b1  = (const float*)d_in[6];
    const float* W2  = (const float*)d_in[7];
    // d_in[8] = b2: constant per softmax row -> drops out (shift invariance)
    const float* Ww1 = (const float*)d_in[9];
    const float* bw1 = (const float*)d_in[10];
    const float* Wd1 = (const float*)d_in[11];
    const float* bd1 = (const float*)d_in[12];
    const float* Ww2 = (const float*)d_in[13];
    const float* bw2 = (const float*)d_in[14];
    const float* Wd2 = (const float*)d_in[15];
    const float* bd2 = (const float*)d_in[16];
    const float* Wf1 = (const float*)d_in[17];
    const float* bf1 = (const float*)d_in[18];
    const float* Wf2 = (const float*)d_in[19];
    const float* bf2 = (const float*)d_in[20];
    const float* ln1g = (const float*)d_in[21];
    const float* ln1b = (const float*)d_in[22];
    const float* ln2g = (const float*)d_in[23];
    const float* ln2b = (const float*)d_in[24];
    const float* ln3g = (const float*)d_in[25];
    const float* ln3b = (const float*)d_in[26];
    float* out = (float*)d_out;

    float* ws = (float*)d_ws;
    const size_t RD = (size_t)R * D;        // 131072
    const size_t SSz = (size_t)B * S * S;   // 262144
    float* xw   = ws;             // v/k/q projection of x (self-attn, shared)
    float* qa   = xw   + RD;
    float* kb   = qa   + RD;
    float* sbuf = kb   + RD;      // SSz
    float* attn = sbuf + SSz;     // SSz
    float* ao   = attn + SSz;
    float* aop  = ao   + RD;
    float* out1 = aop  + RD;
    float* q2w  = out1 + RD;
    float* kv2w = q2w  + RD;
    float* qa2  = kv2w + RD;
    float* kb2  = qa2  + RD;
    float* qb2  = kb2  + RD;
    float* ka2  = qb2  + RD;
    float* out2 = ka2  + RD;
    float* ffh  = out2 + RD;      // R*DFF
    float* ffo  = ffh  + (size_t)R * DFF;

    const dim3 blk(256);

    // ---- self-attention block ----
    mm_kernel<128,128,false><<<R/8, blk, 0, stream>>>(x,   Ww1, bw1,     xw);
    mm_kernel<128,128,false><<<R/8, blk, 0, stream>>>(xw,  W1q, b1,      qa);   // b1 folded
    mm_kernel<128,128,false><<<R/8, blk, 0, stream>>>(xw,  W1k, nullptr, kb);
    pairwise_kernel<<<dim3(S/32, S/32, B), blk, 0, stream>>>(qa, kb, W2, sbuf, 0);
    softmax_kernel<true><<<B*S, blk, 0, stream>>>(sbuf, com_mask, attn);        // sym via transpose
    bmm_av_kernel<<<R/8, blk, 0, stream>>>(attn, xw, ao);
    mm_kernel<128,128,false><<<R/8, blk, 0, stream>>>(ao,  Wd1, bd1,     aop);
    lnres_kernel<<<R, 64, 0, stream>>>(aop, x, ln1g, ln1b, out1);

    // ---- cross-attention block ----
    mm_kernel<128,128,false><<<R/8, blk, 0, stream>>>(out1, Ww2, bw2,     q2w);
    mm_kernel<128,128,false><<<R/8, blk, 0, stream>>>(enc,  Ww2, bw2,     kv2w);
    mm_kernel<128,128,false><<<R/8, blk, 0, stream>>>(q2w,  W1q, b1,      qa2);
    mm_kernel<128,128,false><<<R/8, blk, 0, stream>>>(kv2w, W1k, nullptr, kb2);
    mm_kernel<128,128,false><<<R/8, blk, 0, stream>>>(q2w,  W1k, b1,      qb2);
    mm_kernel<128,128,false><<<R/8, blk, 0, stream>>>(kv2w, W1q, nullptr, ka2);
    pairwise_kernel<<<dim3(S/32, S/32, B), blk, 0, stream>>>(qa2, kb2, W2, sbuf, 0);
    pairwise_kernel<<<dim3(S/32, S/32, B), blk, 0, stream>>>(qb2, ka2, W2, sbuf, 1);
    softmax_kernel<false><<<B*S, blk, 0, stream>>>(sbuf, dec_mask, attn);
    bmm_av_kernel<<<R/8, blk, 0, stream>>>(attn, kv2w, ao);
    mm_kernel<128,128,false><<<R/8, blk, 0, stream>>>(ao, Wd2, bd2, aop);
    lnres_kernel<<<R, 64, 0, stream>>>(aop, out1, ln2g, ln2b, out2);

    // ---- ffn ----
    mm_kernel<128,512,true ><<<R/2, blk, 0, stream>>>(out2, Wf1, bf1, ffh);
    mm_kernel<512,128,false><<<R/8, blk, 0, stream>>>(ffh,  Wf2, bf2, ffo);
    lnres_kernel<<<R, 64, 0, stream>>>(ffo, out2, ln3g, ln3b, out);
}

// Round 2
// 236.851 us; speedup vs baseline: 1.2256x; 1.2256x over previous
//
#include <hip/hip_runtime.h>
#include <math.h>

// DecoderLayer: B=4,N=1,S=256,D=128,H=128,DFF=512, fp32 end-to-end.
// Round-1: fuse 23 dispatches -> 13.
//  - projection chains folded: (x@Ww+bw)@W1q == x@(Ww@W1q) + (bw@W1q); combined
//    weights computed once per call by a tiny prep kernel (weights are inputs).
//  - one proj kernel produces up to 3 outputs (shared LDS A-tile).
//  - softmax fused into the attn@V kernel (block already holds full rows).
//  - output projection fused with residual add + layernorm.
//  - both symmetric cross pairwise terms in ONE kernel (two-phase LDS reuse).
//  - self-attn symmetry: term2[q,k] == term1[k,q] -> transpose read in softmax.
//  - b2 drops (softmax shift invariance); b1 folded into q-side bias combos.

#define LN_EPS 1e-6f
#define NEGV  (-1e9f)

constexpr int B = 4, S = 256, D = 128, H = 128, DFF = 512;
constexpr int R = B * S; // 1024 rows (N=1)

struct ProjArgs    { const float* W[3]; const float* bias[3]; float* out[3]; };
struct PrepMatArgs { const float* L[4]; const float* Rm[4]; float* out[4]; };
struct PrepBiasArgs{ const float* bw[6]; const float* Wr[6]; float* out[6]; int addb1[6]; };

// ---- prep: Cmat[m] = L[m] @ Rm[m]  (all 128x128), grid (16, 4) ----
__global__ __launch_bounds__(256) void prep_mat_kernel(PrepMatArgs p) {
    const int m = blockIdx.y;
    const float* __restrict__ A = p.L[m];
    const float* __restrict__ W = p.Rm[m];
    float* __restrict__ out = p.out[m];
    __shared__ float Ash[8 * 128];
    const int r0 = blockIdx.x * 8;
    const float4* Ag = (const float4*)(A + (size_t)r0 * 128);
    for (int i = threadIdx.x; i < 8 * 128 / 4; i += 256) ((float4*)Ash)[i] = Ag[i];
    __syncthreads();
    const int lr = threadIdx.x >> 5, c4 = threadIdx.x & 31;
    const float4* W4 = (const float4*)W;
    float4 acc = make_float4(0.f, 0.f, 0.f, 0.f);
    #pragma unroll 8
    for (int k = 0; k < 128; ++k) {
        const float a = Ash[lr * 128 + k];
        const float4 w = W4[k * 32 + c4];
        acc.x = fmaf(a, w.x, acc.x); acc.y = fmaf(a, w.y, acc.y);
        acc.z = fmaf(a, w.z, acc.z); acc.w = fmaf(a, w.w, acc.w);
    }
    ((float4*)out)[(size_t)(r0 + lr) * 32 + c4] = acc;
}

// ---- prep: bb[j] = bw[j] @ Wr[j] (+ b1), grid (6), 128 threads ----
__global__ __launch_bounds__(128) void prep_bias_kernel(PrepBiasArgs p, const float* __restrict__ b1) {
    const int j = blockIdx.x, c = threadIdx.x;
    const float* __restrict__ bw = p.bw[j];
    const float* __restrict__ Wr = p.Wr[j];
    float s = p.addb1[j] ? b1[c] : 0.f;
    #pragma unroll 8
    for (int k = 0; k < 128; ++k) s = fmaf(bw[k], Wr[k * 128 + c], s);
    p.out[j][c] = s;
}

// ---- multi-output projection: out[g] = A @ W[g] + bias[g], grid (R/8, ngroups) ----
__global__ __launch_bounds__(256) void proj_kernel(const float* __restrict__ A, ProjArgs p) {
    const int g = blockIdx.y;
    const float* __restrict__ W = p.W[g];
    const float* __restrict__ bias = p.bias[g];
    float* __restrict__ out = p.out[g];
    __shared__ float Ash[8 * 128];
    const int r0 = blockIdx.x * 8;
    const float4* Ag = (const float4*)(A + (size_t)r0 * 128);
    for (int i = threadIdx.x; i < 8 * 128 / 4; i += 256) ((float4*)Ash)[i] = Ag[i];
    __syncthreads();
    const int lr = threadIdx.x >> 5, c4 = threadIdx.x & 31;
    const float4* W4 = (const float4*)W;
    float4 acc = ((const float4*)bias)[c4];
    #pragma unroll 8
    for (int k = 0; k < 128; ++k) {
        const float a = Ash[lr * 128 + k];
        const float4 w = W4[k * 32 + c4];
        acc.x = fmaf(a, w.x, acc.x); acc.y = fmaf(a, w.y, acc.y);
        acc.z = fmaf(a, w.z, acc.z); acc.w = fmaf(a, w.w, acc.w);
    }
    ((float4*)out)[(size_t)(r0 + lr) * 32 + c4] = acc;
}

// ---- generic mm (used for ffn1): out[R,C] = A[R,K]@W[K,C]+bias, optional relu ----
template<int K, int C, bool RELU>
__global__ __launch_bounds__(256) void mm_kernel(
    const float* __restrict__ A, const float* __restrict__ W,
    const float* __restrict__ bias, float* __restrict__ out)
{
    constexpr int C4 = C / 4;
    constexpr int ROWS = 256 / C4;
    __shared__ float Ash[ROWS * K];
    const int r0 = blockIdx.x * ROWS;
    const float4* Ag = (const float4*)(A + (size_t)r0 * K);
    for (int i = threadIdx.x; i < ROWS * K / 4; i += 256) ((float4*)Ash)[i] = Ag[i];
    __syncthreads();
    const int lr = threadIdx.x / C4, c4 = threadIdx.x % C4;
    const float4* W4 = (const float4*)W;
    float4 acc = ((const float4*)bias)[c4];
    #pragma unroll 8
    for (int k = 0; k < K; ++k) {
        const float a = Ash[lr * K + k];
        const float4 w = W4[k * C4 + c4];
        acc.x = fmaf(a, w.x, acc.x); acc.y = fmaf(a, w.y, acc.y);
        acc.z = fmaf(a, w.z, acc.z); acc.w = fmaf(a, w.w, acc.w);
    }
    if (RELU) {
        acc.x = fmaxf(acc.x, 0.f); acc.y = fmaxf(acc.y, 0.f);
        acc.z = fmaxf(acc.z, 0.f); acc.w = fmaxf(acc.w, 0.f);
    }
    ((float4*)out)[(size_t)(r0 + lr) * C4 + c4] = acc;
}

// ---- pairwise accumulate helper (float4 over h) ----
#define PW_STEP(AP0, AP1, BP0, BP1)                                            \
    {                                                                          \
        const float4 w  = *(const float4*)(W2s + h);                           \
        const float4 a0 = *(const float4*)((AP0) + h);                         \
        const float4 a1 = *(const float4*)((AP1) + h);                         \
        const float4 b0 = *(const float4*)((BP0) + h);                         \
        const float4 b1 = *(const float4*)((BP1) + h);                         \
        acc00 = fmaf(fmaxf(a0.x+b0.x,0.f),w.x,acc00); acc00 = fmaf(fmaxf(a0.y+b0.y,0.f),w.y,acc00); \
        acc00 = fmaf(fmaxf(a0.z+b0.z,0.f),w.z,acc00); acc00 = fmaf(fmaxf(a0.w+b0.w,0.f),w.w,acc00); \
        acc01 = fmaf(fmaxf(a0.x+b1.x,0.f),w.x,acc01); acc01 = fmaf(fmaxf(a0.y+b1.y,0.f),w.y,acc01); \
        acc01 = fmaf(fmaxf(a0.z+b1.z,0.f),w.z,acc01); acc01 = fmaf(fmaxf(a0.w+b1.w,0.f),w.w,acc01); \
        acc10 = fmaf(fmaxf(a1.x+b0.x,0.f),w.x,acc10); acc10 = fmaf(fmaxf(a1.y+b0.y,0.f),w.y,acc10); \
        acc10 = fmaf(fmaxf(a1.z+b0.z,0.f),w.z,acc10); acc10 = fmaf(fmaxf(a1.w+b0.w,0.f),w.w,acc10); \
        acc11 = fmaf(fmaxf(a1.x+b1.x,0.f),w.x,acc11); acc11 = fmaf(fmaxf(a1.y+b1.y,0.f),w.y,acc11); \
        acc11 = fmaf(fmaxf(a1.z+b1.z,0.f),w.z,acc11); acc11 = fmaf(fmaxf(a1.w+b1.w,0.f),w.w,acc11); \
    }

// ---- self pairwise: S[b,q,k] = sum_h relu(Aq[q,h]+Bk[k,h])*W2[h]; 32x32 tile ----
__global__ __launch_bounds__(256) void pairwise_self_kernel(
    const float* __restrict__ Aq, const float* __restrict__ Bk,
    const float* __restrict__ W2, float* __restrict__ Sout)
{
    constexpr int LDW = H + 4; // pad to break bank aliasing, keeps 16B align
    __shared__ __align__(16) float As[32 * LDW];
    __shared__ __align__(16) float Bs[32 * LDW];
    __shared__ __align__(16) float W2s[H];
    const int b = blockIdx.z, q0 = blockIdx.y * 32, k0 = blockIdx.x * 32;
    const int tid = threadIdx.x, bS = b * S;

    for (int i = tid; i < 32 * (H / 4); i += 256) {
        const int r = i >> 5, c4 = i & 31;
        ((float4*)(As + r * LDW))[c4] = ((const float4*)(Aq + (size_t)(bS + q0 + r) * H))[c4];
        ((float4*)(Bs + r * LDW))[c4] = ((const float4*)(Bk + (size_t)(bS + k0 + r) * H))[c4];
    }
    if (tid < H / 4) ((float4*)W2s)[tid] = ((const float4*)W2)[tid];
    __syncthreads();

    const int tx = tid & 15, ty = tid >> 4;
    const float* A0 = As + (2 * ty) * LDW; const float* A1 = A0 + LDW;
    const float* B0 = Bs + (2 * tx) * LDW; const float* B1 = B0 + LDW;
    float acc00 = 0.f, acc01 = 0.f, acc10 = 0.f, acc11 = 0.f;
    #pragma unroll 4
    for (int h = 0; h < H; h += 4) PW_STEP(A0, A1, B0, B1);

    const size_t base = (size_t)(bS + q0 + 2 * ty) * S + (k0 + 2 * tx);
    *(float2*)(Sout + base)     = make_float2(acc00, acc01);
    *(float2*)(Sout + base + S) = make_float2(acc10, acc11);
}

// ---- cross pairwise, BOTH symmetric terms, two-phase LDS reuse ----
__global__ __launch_bounds__(256) void pairwise_cross2_kernel(
    const float* __restrict__ Qa, const float* __restrict__ Kb,
    const float* __restrict__ Qb, const float* __restrict__ Ka,
    const float* __restrict__ W2, float* __restrict__ Sout)
{
    constexpr int LDW = H + 4;
    __shared__ __align__(16) float As[32 * LDW];
    __shared__ __align__(16) float Bs[32 * LDW];
    __shared__ __align__(16) float W2s[H];
    const int b = blockIdx.z, q0 = blockIdx.y * 32, k0 = blockIdx.x * 32;
    const int tid = threadIdx.x, bS = b * S;
    const int tx = tid & 15, ty = tid >> 4;
    const float* A0 = As + (2 * ty) * LDW; const float* A1 = A0 + LDW;
    const float* B0 = Bs + (2 * tx) * LDW; const float* B1 = B0 + LDW;
    float acc00 = 0.f, acc01 = 0.f, acc10 = 0.f, acc11 = 0.f;

    // phase 1: relu(Qa[q]+Kb[k])
    for (int i = tid; i < 32 * (H / 4); i += 256) {
        const int r = i >> 5, c4 = i & 31;
        ((float4*)(As + r * LDW))[c4] = ((const float4*)(Qa + (size_t)(bS + q0 + r) * H))[c4];
        ((float4*)(Bs + r * LDW))[c4] = ((const float4*)(Kb + (size_t)(bS + k0 + r) * H))[c4];
    }
    if (tid < H / 4) ((float4*)W2s)[tid] = ((const float4*)W2)[tid];
    __syncthreads();
    #pragma unroll 4
    for (int h = 0; h < H; h += 4) PW_STEP(A0, A1, B0, B1);
    __syncthreads();

    // phase 2: relu(Qb[q]+Ka[k]) into the same accumulators
    for (int i = tid; i < 32 * (H / 4); i += 256) {
        const int r = i >> 5, c4 = i & 31;
        ((float4*)(As + r * LDW))[c4] = ((const float4*)(Qb + (size_t)(bS + q0 + r) * H))[c4];
        ((float4*)(Bs + r * LDW))[c4] = ((const float4*)(Ka + (size_t)(bS + k0 + r) * H))[c4];
    }
    __syncthreads();
    #pragma unroll 4
    for (int h = 0; h < H; h += 4) PW_STEP(A0, A1, B0, B1);

    const size_t base = (size_t)(bS + q0 + 2 * ty) * S + (k0 + 2 * tx);
    *(float2*)(Sout + base)     = make_float2(acc00, acc01);
    *(float2*)(Sout + base + S) = make_float2(acc10, acc11);
}

// ---- fused softmax + attn@V: 8 rows/block; SYM adds transpose term ----
template<bool SYM>
__global__ __launch_bounds__(256) void softmax_av_kernel(
    const float* __restrict__ Sin, const float* __restrict__ mask,
    const float* __restrict__ V, float* __restrict__ out)
{
    __shared__ float Ash[8 * S];
    const int r0 = blockIdx.x * 8, b = r0 >> 8, bS = b * S, tid = threadIdx.x;

    for (int i = tid; i < 8 * S; i += 256) {
        const int r = i >> 8, k = i & (S - 1);
        const int row = r0 + r, q = row & (S - 1);
        float l = Sin[(size_t)row * S + k];
        if (SYM) l += Sin[(size_t)(bS + k) * S + q];
        l += mask[(size_t)row * S + k] * NEGV;
        Ash[i] = l;
    }
    __syncthreads();
    {
        const int g = tid >> 5, c = tid & 31;
        float* rowp = Ash + g * S;
        float m = -INFINITY;
        for (int k = c; k < S; k += 32) m = fmaxf(m, rowp[k]);
        for (int o = 16; o; o >>= 1) m = fmaxf(m, __shfl_xor(m, o, 32));
        float s = 0.f;
        for (int k = c; k < S; k += 32) { const float e = __expf(rowp[k] - m); rowp[k] = e; s += e; }
        for (int o = 16; o; o >>= 1) s += __shfl_xor(s, o, 32);
        const float rinv = 1.f / s;
        for (int k = c; k < S; k += 32) rowp[k] *= rinv;
    }
    __syncthreads();
    const int lr = tid >> 5, c4 = tid & 31;
    const float4* V4 = (const float4*)(V + (size_t)bS * D);
    float4 acc = make_float4(0.f, 0.f, 0.f, 0.f);
    #pragma unroll 8
    for (int k = 0; k < S; ++k) {
        const float a = Ash[lr * S + k];
        const float4 v = V4[k * 32 + c4];
        acc.x = fmaf(a, v.x, acc.x); acc.y = fmaf(a, v.y, acc.y);
        acc.z = fmaf(a, v.z, acc.z); acc.w = fmaf(a, v.w, acc.w);
    }
    ((float4*)out)[(size_t)(r0 + lr) * 32 + c4] = acc;
}

// ---- fused out-proj (+bias) + residual + layernorm; C=128, templated K ----
template<int K>
__global__ __launch_bounds__(256) void outln_kernel(
    const float* __restrict__ A, const float* __restrict__ W,
    const float* __restrict__ bias, const float* __restrict__ Res,
    const float* __restrict__ g, const float* __restrict__ be,
    float* __restrict__ out)
{
    __shared__ float Ash[8 * K];
    const int r0 = blockIdx.x * 8, tid = threadIdx.x;
    const float4* Ag = (const float4*)(A + (size_t)r0 * K);
    for (int i = tid; i < 8 * K / 4; i += 256) ((float4*)Ash)[i] = Ag[i];
    __syncthreads();
    const int lr = tid >> 5, c4 = tid & 31;
    const float4* W4 = (const float4*)W;
    float4 acc = ((const float4*)bias)[c4];
    #pragma unroll 8
    for (int k = 0; k < K; ++k) {
        const float a = Ash[lr * K + k];
        const float4 w = W4[k * 32 + c4];
        acc.x = fmaf(a, w.x, acc.x); acc.y = fmaf(a, w.y, acc.y);
        acc.z = fmaf(a, w.z, acc.z); acc.w = fmaf(a, w.w, acc.w);
    }
    const float4 r4 = ((const float4*)(Res + (size_t)(r0 + lr) * 128))[c4];
    const float x0 = acc.x + r4.x, x1 = acc.y + r4.y, x2 = acc.z + r4.z, x3 = acc.w + r4.w;
    float s  = x0 + x1 + x2 + x3;
    float s2 = x0 * x0 + x1 * x1 + x2 * x2 + x3 * x3;
    for (int o = 16; o; o >>= 1) { s += __shfl_xor(s, o, 32); s2 += __shfl_xor(s2, o, 32); }
    const float m = s * (1.f / 128), var = s2 * (1.f / 128) - m * m;
    const float rs = rsqrtf(var + LN_EPS);
    const float4 gv = ((const float4*)g)[c4], bv = ((const float4*)be)[c4];
    float4 o4;
    o4.x = (x0 - m) * rs * gv.x + bv.x; o4.y = (x1 - m) * rs * gv.y + bv.y;
    o4.z = (x2 - m) * rs * gv.z + bv.z; o4.w = (x3 - m) * rs * gv.w + bv.w;
    ((float4*)out)[(size_t)(r0 + lr) * 32 + c4] = o4;
}

extern "C" void kernel_launch(void* const* d_in, const int* in_sizes, int n_in,
                              void* d_out, int out_size, void* d_ws, size_t ws_size,
                              hipStream_t stream) {
    (void)in_sizes; (void)n_in; (void)out_size; (void)ws_size;
    const float* x        = (const float*)d_in[0];
    const float* enc      = (const float*)d_in[1];
    const float* com_mask = (const float*)d_in[2];
    const float* dec_mask = (const float*)d_in[3];
    const float* W1q = (const float*)d_in[4];
    const float* W1k = (const float*)d_in[5];
    const float* b1  = (const float*)d_in[6];
    const float* W2  = (const float*)d_in[7];
    // d_in[8] = b2: per-row constant -> softmax shift invariance, dropped
    const float* Ww1 = (const float*)d_in[9];
    const float* bw1 = (const float*)d_in[10];
    const float* Wd1 = (const float*)d_in[11];
    const float* bd1 = (const float*)d_in[12];
    const float* Ww2 = (const float*)d_in[13];
    const float* bw2 = (const float*)d_in[14];
    const float* Wd2 = (const float*)d_in[15];
    const float* bd2 = (const float*)d_in[16];
    const float* Wf1 = (const float*)d_in[17];
    const float* bf1 = (const float*)d_in[18];
    const float* Wf2 = (const float*)d_in[19];
    const float* bf2 = (const float*)d_in[20];
    const float* ln1g = (const float*)d_in[21];
    const float* ln1b = (const float*)d_in[22];
    const float* ln2g = (const float*)d_in[23];
    const float* ln2b = (const float*)d_in[24];
    const float* ln3g = (const float*)d_in[25];
    const float* ln3b = (const float*)d_in[26];
    float* out = (float*)d_out;

    float* ws = (float*)d_ws;
    const size_t RD  = (size_t)R * D;      // 131072
    const size_t SSz = (size_t)B * S * S;  // 262144
    const size_t WW  = 128 * 128;          // 16384
    float* C1q  = ws;              // Ww1@W1q
    float* C1k  = C1q  + WW;       // Ww1@W1k
    float* C2q  = C1k  + WW;       // Ww2@W1q
    float* C2k  = C2q  + WW;       // Ww2@W1k
    float* bb   = C2k  + WW;       // 6 combined bias vectors [6][128]
    float* xw   = bb   + 1024;
    float* qa   = xw   + RD;
    float* kb   = qa   + RD;
    float* kv2w = kb   + RD;
    float* kb2  = kv2w + RD;
    float* ka2  = kb2  + RD;
    float* qa2  = ka2  + RD;
    float* qb2  = qa2  + RD;
    float* sbuf = qb2  + RD;       // SSz
    float* ao   = sbuf + SSz;
    float* out1 = ao   + RD;
    float* out2 = out1 + RD;
    float* ffh  = out2 + RD;       // R*DFF

    // 1-2: weight/bias pre-combination (tiny; weights are per-call inputs)
    PrepMatArgs pm;
    pm.L[0] = Ww1; pm.Rm[0] = W1q; pm.out[0] = C1q;
    pm.L[1] = Ww1; pm.Rm[1] = W1k; pm.out[1] = C1k;
    pm.L[2] = Ww2; pm.Rm[2] = W1q; pm.out[2] = C2q;
    pm.L[3] = Ww2; pm.Rm[3] = W1k; pm.out[3] = C2k;
    prep_mat_kernel<<<dim3(16, 4), 256, 0, stream>>>(pm);

    PrepBiasArgs pb;
    pb.bw[0] = bw1; pb.Wr[0] = W1q; pb.out[0] = bb + 0 * 128; pb.addb1[0] = 1; // qa
    pb.bw[1] = bw1; pb.Wr[1] = W1k; pb.out[1] = bb + 1 * 128; pb.addb1[1] = 0; // kb
    pb.bw[2] = bw2; pb.Wr[2] = W1q; pb.out[2] = bb + 2 * 128; pb.addb1[2] = 1; // qa2
    pb.bw[3] = bw2; pb.Wr[3] = W1k; pb.out[3] = bb + 3 * 128; pb.addb1[3] = 1; // qb2
    pb.bw[4] = bw2; pb.Wr[4] = W1k; pb.out[4] = bb + 4 * 128; pb.addb1[4] = 0; // kb2
    pb.bw[5] = bw2; pb.Wr[5] = W1q; pb.out[5] = bb + 5 * 128; pb.addb1[5] = 0; // ka2
    prep_bias_kernel<<<6, 128, 0, stream>>>(pb, b1);

    // 3: self projections  x -> [xw | qa | kb]
    ProjArgs p1;
    p1.W[0] = Ww1; p1.bias[0] = bw1;          p1.out[0] = xw;
    p1.W[1] = C1q; p1.bias[1] = bb + 0 * 128; p1.out[1] = qa;
    p1.W[2] = C1k; p1.bias[2] = bb + 1 * 128; p1.out[2] = kb;
    proj_kernel<<<dim3(R / 8, 3), 256, 0, stream>>>(x, p1);

    // 4: cross k-side projections  enc -> [kv2w | kb2 | ka2]  (independent of block 1)
    ProjArgs p2;
    p2.W[0] = Ww2; p2.bias[0] = bw2;          p2.out[0] = kv2w;
    p2.W[1] = C2k; p2.bias[1] = bb + 4 * 128; p2.out[1] = kb2;
    p2.W[2] = C2q; p2.bias[2] = bb + 5 * 128; p2.out[2] = ka2;
    proj_kernel<<<dim3(R / 8, 3), 256, 0, stream>>>(enc, p2);

    // 5-7: self-attention
    pairwise_self_kernel<<<dim3(S / 32, S / 32, B), 256, 0, stream>>>(qa, kb, W2, sbuf);
    softmax_av_kernel<true><<<R / 8, 256, 0, stream>>>(sbuf, com_mask, xw, ao);
    outln_kernel<128><<<R / 8, 256, 0, stream>>>(ao, Wd1, bd1, x, ln1g, ln1b, out1);

    // 8: cross q-side projections  out1 -> [qa2 | qb2]
    ProjArgs p3;
    p3.W[0] = C2q; p3.bias[0] = bb + 2 * 128; p3.out[0] = qa2;
    p3.W[1] = C2k; p3.bias[1] = bb + 3 * 128; p3.out[1] = qb2;
    p3.W[2] = nullptr; p3.bias[2] = nullptr; p3.out[2] = nullptr;
    proj_kernel<<<dim3(R / 8, 2), 256, 0, stream>>>(out1, p3);

    // 9-11: cross-attention
    pairwise_cross2_kernel<<<dim3(S / 32, S / 32, B), 256, 0, stream>>>(qa2, kb2, qb2, ka2, W2, sbuf);
    softmax_av_kernel<false><<<R / 8, 256, 0, stream>>>(sbuf, dec_mask, kv2w, ao);
    outln_kernel<128><<<R / 8, 256, 0, stream>>>(ao, Wd2, bd2, out1, ln2g, ln2b, out2);

    // 12-13: ffn
    mm_kernel<128, 512, true><<<R / 2, 256, 0, stream>>>(out2, Wf1, bf1, ffh);
    outln_kernel<512><<<R / 8, 256, 0, stream>>>(ffh, Wf2, bf2, out2, ln3g, ln3b, out);
}